// Round 5
// baseline (125.945 us; speedup 1.0000x reference)
//
#include <hip/hip_runtime.h>
#include <math.h>

#define HW (512*512)
#define TSX 64
#define TSY 16
#define NROW 22              // TSY + 6 halo rows
#define LSTR 76              // dwords per LDS row: 19 quads (18 logical + 1 pad; 19 % 8 = 3 staggers rows)
#define CH_STRIDE (NROW*LSTR)

// ---------------- Kernel 1: per-plane partial sums (global avg pool) ----------------
__global__ __launch_bounds__(256) void k_reduce(const float* __restrict__ x,
                                                float* __restrict__ ws) {
    int bid = blockIdx.x;            // 1024 blocks = 128 planes * 8 chunks
    int plane = bid >> 3, j = bid & 7;
    const float4* xv = (const float4*)x + (size_t)plane * 65536 + (size_t)j * 8192;
    int tid = threadIdx.x;
    float s = 0.f;
    #pragma unroll
    for (int k = 0; k < 32; ++k) {
        float4 v = xv[(size_t)k * 256 + tid];
        s += (v.x + v.y) + (v.z + v.w);
    }
    #pragma unroll
    for (int off = 32; off > 0; off >>= 1) s += __shfl_down(s, off, 64);
    __shared__ float red[4];
    if ((tid & 63) == 0) red[tid >> 6] = s;
    __syncthreads();
    if (tid == 0) ws[bid] = (red[0] + red[1]) + (red[2] + red[3]);
}

// ---------------- Kernel 2: finish pool + channel-attention MLP ----------------
__global__ __launch_bounds__(128) void k_mlp(const float* __restrict__ part,
                                             const float* __restrict__ w1,
                                             const float* __restrict__ b1,
                                             const float* __restrict__ w2,
                                             const float* __restrict__ b2,
                                             float* __restrict__ att_out) {
    __shared__ float pool[128];   // [b][c], b=32, c=4
    __shared__ float hbuf[64];    // [b][r], r=2
    int tid = threadIdx.x;
    float s = 0.f;
    #pragma unroll
    for (int j = 0; j < 8; ++j) s += part[tid * 8 + j];
    pool[tid] = s * (1.f / 262144.f);
    __syncthreads();
    if (tid < 64) {
        int b = tid >> 1, r = tid & 1;
        float h = b1[r];
        #pragma unroll
        for (int c = 0; c < 4; ++c) h += w1[r * 4 + c] * pool[b * 4 + c];
        hbuf[tid] = fmaxf(h, 0.f);          // hbuf[b*2+r]
    }
    __syncthreads();
    {
        int b = tid >> 2, c = tid & 3;
        float z = b2[c];
        #pragma unroll
        for (int r = 0; r < 2; ++r) z += w2[c * 2 + r] * hbuf[b * 2 + r];
        att_out[tid] = 1.f / (1.f + __expf(-z));   // att[b*4+c]
    }
}

// ---------------- Kernel 3: fused gate + 1x1 conv + 7x7 conv + sigmoid gate ----------------
// Tile 64x16, 256 threads, thread owns 4 cols x 1 row (tx4=tid&15, ty=tid>>4).
// LDS 20.1 KB -> 8 blocks/CU (32 waves). No XOR swizzle: conv reads are
// phase-conflict-free (16 lanes x 16 consecutive quads = every bank twice);
// LSTR=76 (19 quads, 3 mod 8) staggers rows for the staging writes.
// Single-row ownership: conv loop is branch-free (dy == k); center row
// captured into registers at k==3 so the epilogue does zero LDS reads.
__global__ __launch_bounds__(256, 8) void k_fused(const float* __restrict__ x,
                                                  const float* __restrict__ conv_w,
                                                  const float* __restrict__ conv_b,
                                                  const float* __restrict__ sa_w,
                                                  const float* __restrict__ sa_b,
                                                  const float* __restrict__ att,
                                                  float* __restrict__ out) {
    __shared__ float s_out[3 * CH_STRIDE];   // 20,064 B
    int tid = threadIdx.x;
    int b = blockIdx.z;
    int ty0 = blockIdx.y * TSY, tx0 = blockIdx.x * TSX;

    // uniform params (scalar loads)
    float kw[12], kb[3];
    #pragma unroll
    for (int t = 0; t < 12; ++t) kw[t] = conv_w[t] * att[b * 4 + (t & 3)];
    #pragma unroll
    for (int o = 0; o < 3; ++o) kb[o] = conv_b[o];
    float sbias = sa_b[0];

    // ---- Stage: gated 1x1 conv for tile+halo into LDS (b128 writes) ----
    // logical: row r (0..21) = gy-(ty0-3); quad q (0..17), dword cc = gx-(tx0-4)
    const float* xb = x + (size_t)b * 4 * HW;
    for (int idx = tid; idx < NROW * 18; idx += 256) {
        int r = idx / 18, q = idx - r * 18;
        int gy = ty0 - 3 + r;
        int gx0 = tx0 - 4 + q * 4;
        float4 o0 = make_float4(0.f, 0.f, 0.f, 0.f), o1 = o0, o2 = o0;
        if ((unsigned)gy < 512u && (unsigned)gx0 <= 508u) {
            size_t off = (size_t)gy * 512 + gx0;
            float4 X0 = *(const float4*)(xb + off);
            float4 X1 = *(const float4*)(xb + HW + off);
            float4 X2 = *(const float4*)(xb + 2 * HW + off);
            float4 X3 = *(const float4*)(xb + 3 * HW + off);
#define DO1(comp) \
            o0.comp = kb[0] + kw[0]*X0.comp + kw[1]*X1.comp + kw[2]*X2.comp + kw[3]*X3.comp; \
            o1.comp = kb[1] + kw[4]*X0.comp + kw[5]*X1.comp + kw[6]*X2.comp + kw[7]*X3.comp; \
            o2.comp = kb[2] + kw[8]*X0.comp + kw[9]*X1.comp + kw[10]*X2.comp + kw[11]*X3.comp;
            DO1(x) DO1(y) DO1(z) DO1(w)
#undef DO1
        }
        int base = r * LSTR + (q << 2);
        *(float4*)(&s_out[base])                 = o0;
        *(float4*)(&s_out[base + CH_STRIDE])     = o1;
        *(float4*)(&s_out[base + 2 * CH_STRIDE]) = o2;
    }
    __syncthreads();

    // ---- 7x7 conv: thread computes 4 px in one row; 3 b128 LDS reads / input row ----
    int tx4 = tid & 15, ty = tid >> 4;    // out row ty0+ty, cols tx0+tx4*4 ..+3
    float acc[4] = {0.f, 0.f, 0.f, 0.f};
    float ctr[3][4];                      // center (1x1-conv) values per channel

    #pragma unroll
    for (int ch = 0; ch < 3; ++ch) {
        const float* sbp = &s_out[ch * CH_STRIDE];
        const float* wp = sa_w + ch * 49;
        #pragma unroll
        for (int k = 0; k < 7; ++k) {
            int rb = (ty + k) * LSTR + (tx4 << 2);   // logical row ty+k; dy == k
            float4 va = *(const float4*)(sbp + rb);
            float4 vb = *(const float4*)(sbp + rb + 4);
            float4 vc = *(const float4*)(sbp + rb + 8);
            if (k == 3) {                 // center row: vb holds the 4 output px
                ctr[ch][0] = vb.x; ctr[ch][1] = vb.y; ctr[ch][2] = vb.z; ctr[ch][3] = vb.w;
            }
            float v[12] = {va.x, va.y, va.z, va.w,
                           vb.x, vb.y, vb.z, vb.w,
                           vc.x, vc.y, vc.z, vc.w};
            #pragma unroll
            for (int dx = 0; dx < 7; ++dx) {
                float wv = wp[k * 7 + dx];   // uniform -> s_load
                #pragma unroll
                for (int j = 0; j < 4; ++j)
                    acc[j] += wv * v[j + dx + 1];
            }
        }
    }

    // ---- Epilogue: sigmoid gate + b128 stores (centers already in regs) ----
    float g[4];
    #pragma unroll
    for (int j = 0; j < 4; ++j) g[j] = 1.f / (1.f + __expf(-(acc[j] + sbias)));
    float* ob = out + (size_t)b * 3 * HW;
    size_t off = (size_t)(ty0 + ty) * 512 + (tx0 + tx4 * 4);
    #pragma unroll
    for (int ch = 0; ch < 3; ++ch) {
        float4 c;
        c.x = ctr[ch][0] * g[0]; c.y = ctr[ch][1] * g[1];
        c.z = ctr[ch][2] * g[2]; c.w = ctr[ch][3] * g[3];
        *(float4*)(ob + (size_t)ch * HW + off) = c;
    }
}

extern "C" void kernel_launch(void* const* d_in, const int* in_sizes, int n_in,
                              void* d_out, int out_size, void* d_ws, size_t ws_size,
                              hipStream_t stream) {
    const float* x      = (const float*)d_in[0];
    const float* ca_w1  = (const float*)d_in[1];
    const float* ca_b1  = (const float*)d_in[2];
    const float* ca_w2  = (const float*)d_in[3];
    const float* ca_b2  = (const float*)d_in[4];
    const float* conv_w = (const float*)d_in[5];
    const float* conv_b = (const float*)d_in[6];
    const float* sa_w   = (const float*)d_in[7];
    const float* sa_b   = (const float*)d_in[8];
    float* ws  = (float*)d_ws;
    float* out = (float*)d_out;

    hipLaunchKernelGGL(k_reduce, dim3(1024), dim3(256), 0, stream, x, ws);
    hipLaunchKernelGGL(k_mlp, dim3(1), dim3(128), 0, stream,
                       ws, ca_w1, ca_b1, ca_w2, ca_b2, ws + 1024);
    hipLaunchKernelGGL(k_fused, dim3(8, 32, 32), dim3(256), 0, stream,
                       x, conv_w, conv_b, sa_w, sa_b, ws + 1024, out);
}